// Round 1
// baseline (30.233 us; speedup 1.0000x reference)
//
#include <hip/hip_runtime.h>
#include <stdint.h>

// ---------------------------------------------------------------------------
// SelectiveDropout: out[b,d] = in[b,d] * scale[d]
//   scale[d] = 1 unless d in neuron_indices; for listed columns,
//   scale = (u < 0.1) ? 0 : 1/0.9 with u from jax.random.uniform(key(42),(2048,))
//   duplicates: last write wins (numpy scatter semantics).
//
// RNG: Threefry-2x32, 20 rounds, key = (0, 42).
// THREEFRY_PARTITIONABLE=1 reproduces modern JAX (>=0.5 default):
//   bits[i] = o0 ^ o1 of threefry(x0=hi64(i)=0, x1=lo64(i)=i)
// =0 reproduces legacy mode: counts split in halves, i<1024 -> o0, else o1.
// ---------------------------------------------------------------------------

#define THREEFRY_PARTITIONABLE 1
#define D_DIM 4096

__device__ __forceinline__ uint32_t rotl32(uint32_t v, uint32_t n) {
  return (v << n) | (v >> (32u - n));
}

__device__ __forceinline__ void threefry2x32(uint32_t x0, uint32_t x1,
                                             uint32_t& o0, uint32_t& o1) {
  const uint32_t ks0 = 0u;
  const uint32_t ks1 = 42u;
  const uint32_t ks2 = 0u ^ 42u ^ 0x1BD11BDAu;

  x0 += ks0;
  x1 += ks1;

#define TF_GROUP(a, b, c, d)                           \
  x0 += x1; x1 = rotl32(x1, a); x1 ^= x0;              \
  x0 += x1; x1 = rotl32(x1, b); x1 ^= x0;              \
  x0 += x1; x1 = rotl32(x1, c); x1 ^= x0;              \
  x0 += x1; x1 = rotl32(x1, d); x1 ^= x0;

  TF_GROUP(13, 15, 26, 6)  x0 += ks1; x1 += ks2 + 1u;
  TF_GROUP(17, 29, 16, 24) x0 += ks2; x1 += ks0 + 2u;
  TF_GROUP(13, 15, 26, 6)  x0 += ks0; x1 += ks1 + 3u;
  TF_GROUP(17, 29, 16, 24) x0 += ks1; x1 += ks2 + 4u;
  TF_GROUP(13, 15, 26, 6)  x0 += ks2; x1 += ks0 + 5u;
#undef TF_GROUP

  o0 = x0;
  o1 = x1;
}

__device__ __forceinline__ float jax_uniform_at(int i, int n) {
  uint32_t bits;
#if THREEFRY_PARTITIONABLE
  uint32_t o0, o1;
  threefry2x32(0u, (uint32_t)i, o0, o1);  // counter = i (64-bit iota), hi=0
  bits = o0 ^ o1;
#else
  // legacy: counts iota(n) split into halves: x0 = counts[0:n/2], x1 = counts[n/2:n]
  int half = n >> 1;
  uint32_t o0, o1;
  if (i < half) {
    threefry2x32((uint32_t)i, (uint32_t)(i + half), o0, o1);
    bits = o0;
  } else {
    threefry2x32((uint32_t)(i - half), (uint32_t)i, o0, o1);
    bits = o1;
  }
#endif
  uint32_t fb = (bits >> 9) | 0x3F800000u;
  return __uint_as_float(fb) - 1.0f;
}

// Single-block setup kernel: builds scale[D] in LDS, writes to global ws.
__global__ __launch_bounds__(1024) void build_scale_kernel(
    const int* __restrict__ idx, int n, float* __restrict__ scale_g) {
  __shared__ int winner[D_DIM];
  __shared__ float sc[D_DIM];
  const int t = threadIdx.x;

  for (int d = t; d < D_DIM; d += 1024) {
    winner[d] = -1;
    sc[d] = 1.0f;
  }
  __syncthreads();

  for (int i = t; i < n; i += 1024) {
    atomicMax(&winner[idx[i]], i);  // last write wins => max index wins
  }
  __syncthreads();

  const float inv_keep = (float)(1.0 / (1.0 - 0.1));  // match Python double->f32
  for (int i = t; i < n; i += 1024) {
    int col = idx[i];
    if (winner[col] == i) {
      float u = jax_uniform_at(i, n);
      sc[col] = (u < 0.1f) ? 0.0f : inv_keep;
    }
  }
  __syncthreads();

  for (int d = t; d < D_DIM; d += 1024) {
    scale_g[d] = sc[d];
  }
}

// Streaming multiply: out = in * scale[col], float4 vectorized.
// D=4096 floats = 1024 float4 per row -> col4 = e & 1023.
__global__ __launch_bounds__(256) void apply_scale_kernel(
    const float4* __restrict__ in, const float4* __restrict__ scale4,
    float4* __restrict__ out, int total4) {
  const int stride = gridDim.x * blockDim.x;
  for (int e = blockIdx.x * blockDim.x + threadIdx.x; e < total4; e += stride) {
    float4 v = in[e];
    float4 s = scale4[e & 1023];
    v.x *= s.x;
    v.y *= s.y;
    v.z *= s.z;
    v.w *= s.w;
    out[e] = v;
  }
}

extern "C" void kernel_launch(void* const* d_in, const int* in_sizes, int n_in,
                              void* d_out, int out_size, void* d_ws, size_t ws_size,
                              hipStream_t stream) {
  const float* in = (const float*)d_in[0];
  const int* idx = (const int*)d_in[1];
  float* out = (float*)d_out;
  float* scale = (float*)d_ws;  // D_DIM floats of scratch

  const int n_idx = in_sizes[1];    // 2048
  const int total = in_sizes[0];    // B*D = 16,777,216
  const int total4 = total / 4;

  hipLaunchKernelGGL(build_scale_kernel, dim3(1), dim3(1024), 0, stream,
                     idx, n_idx, scale);

  const int blocks = 2048;  // 8 blocks/CU, grid-stride covers the rest
  hipLaunchKernelGGL(apply_scale_kernel, dim3(blocks), dim3(256), 0, stream,
                     (const float4*)in, (const float4*)scale, (float4*)out,
                     total4);
}